// Round 2
// baseline (184.998 us; speedup 1.0000x reference)
//
#include <hip/hip_runtime.h>
#include <hip/hip_bf16.h>

// out[b,c,hw] = sum_t x[b,t,c,hw] * W[c,t] + bias[c]
// B=16, T=10, C=1024, HW=196 (=49 float4s per map)
// x strides (float4 units): b: 10*50176, t: 50176, plane offset p4 in [0,50176)
//
// R2: 2 outputs per thread (batches b0 and b0+8 share plane offset p4):
//  - weight row W[c][0..9] loaded once, used twice
//  - index math (divide by 49) once per thread
//  - 20 outstanding x-loads/thread for latency hiding
// Grid: x=196 (plane float4s / 256), y=8 (b0). 1568 blocks.

#define T_IN    10
#define HW4     49
#define C_HW4   (1024 * HW4)      // 50176 float4s per (b,t) plane
#define B_STRIDE4 (T_IN * C_HW4)  // float4 stride between batches in x

__global__ __launch_bounds__(256) void conv_over_time_kernel(
    const float* __restrict__ x,
    const float* __restrict__ Wmat,
    const float* __restrict__ bias,
    float* __restrict__ out)
{
    const int p4 = blockIdx.x * 256 + threadIdx.x;   // plane float4 offset [0, 50176)
    const int b0 = blockIdx.y;                       // [0, 8); handles b0 and b0+8
    const int c  = p4 / HW4;                         // map index (magic-mul divide)

    const float4* __restrict__ x4 = (const float4*)x;
    const float*  __restrict__ wrow = Wmat + c * T_IN;

    // Load weight row once (L1/L2 broadcast within wave: <=6 distinct c per wave)
    float w[T_IN];
#pragma unroll
    for (int t = 0; t < T_IN; ++t) w[t] = wrow[t];

    const long base0 = (long)b0 * B_STRIDE4 + p4;
    const long base1 = base0 + 8L * B_STRIDE4;

    const float bb = bias[c];
    float4 acc0 = make_float4(bb, bb, bb, bb);
    float4 acc1 = acc0;

#pragma unroll
    for (int t = 0; t < T_IN; ++t) {
        const float4 v0 = x4[base0 + (long)t * C_HW4];
        const float4 v1 = x4[base1 + (long)t * C_HW4];
        acc0.x = fmaf(v0.x, w[t], acc0.x);
        acc0.y = fmaf(v0.y, w[t], acc0.y);
        acc0.z = fmaf(v0.z, w[t], acc0.z);
        acc0.w = fmaf(v0.w, w[t], acc0.w);
        acc1.x = fmaf(v1.x, w[t], acc1.x);
        acc1.y = fmaf(v1.y, w[t], acc1.y);
        acc1.z = fmaf(v1.z, w[t], acc1.z);
        acc1.w = fmaf(v1.w, w[t], acc1.w);
    }

    float4* __restrict__ out4 = (float4*)out;
    out4[(long)b0 * C_HW4 + p4]       = acc0;
    out4[(long)(b0 + 8) * C_HW4 + p4] = acc1;
}

extern "C" void kernel_launch(void* const* d_in, const int* in_sizes, int n_in,
                              void* d_out, int out_size, void* d_ws, size_t ws_size,
                              hipStream_t stream) {
    const float* x    = (const float*)d_in[0];  // [16,10,1024,14,14]
    const float* Wmat = (const float*)d_in[1];  // [1024,10]
    const float* bias = (const float*)d_in[2];  // [1024]
    float* out = (float*)d_out;                 // [16,1,1024,14,14]

    dim3 grid(C_HW4 / 256, 8);                  // (196, 8)
    conv_over_time_kernel<<<grid, dim3(256), 0, stream>>>(x, Wmat, bias, out);
}

// Round 4
// 181.448 us; speedup vs baseline: 1.0196x; 1.0196x over previous
//
#include <hip/hip_runtime.h>
#include <hip/hip_bf16.h>

// out[b,c,hw] = sum_t x[b,t,c,hw] * W[c,t] + bias[c]
// B=16, T=10, C=1024, HW=196 (=49 float4s per map)
//
// R4 (= R3 fixed): 4 batches per thread (b0, b0+4, b0+8, b0+12):
//  - weight row loaded once, reused 4x
//  - 40 outstanding float4 loads per thread
//  - nontemporal loads (x read-once) and stores (out write-once)
//    via native ext_vector_type (HIP_vector_type rejected by the builtin)
// Grid: (196, 4) = 784 blocks, 256 threads.

#define T_IN      10
#define HW4       49
#define C_HW4     (1024 * HW4)      // 50176 float4s per (b,t) plane
#define B_STRIDE4 (T_IN * C_HW4)    // float4 stride between batches in x

typedef float f32x4 __attribute__((ext_vector_type(4)));

__global__ __launch_bounds__(256) void conv_over_time_kernel(
    const float* __restrict__ x,
    const float* __restrict__ Wmat,
    const float* __restrict__ bias,
    float* __restrict__ out)
{
    const int p4 = blockIdx.x * 256 + threadIdx.x;   // plane float4 offset [0, 50176)
    const int b0 = blockIdx.y;                       // [0, 4); handles b0+{0,4,8,12}
    const int c  = p4 / HW4;                         // magic-mul divide

    const f32x4* __restrict__ x4 = (const f32x4*)x;
    const float* __restrict__ wrow = Wmat + c * T_IN;

    float w[T_IN];
#pragma unroll
    for (int t = 0; t < T_IN; ++t) w[t] = wrow[t];

    const float bb = bias[c];
    f32x4 acc[4];
#pragma unroll
    for (int k = 0; k < 4; ++k) acc[k] = (f32x4){bb, bb, bb, bb};

#pragma unroll
    for (int t = 0; t < T_IN; ++t) {
#pragma unroll
        for (int k = 0; k < 4; ++k) {
            const long off = (long)(b0 + 4 * k) * B_STRIDE4 + (long)t * C_HW4 + p4;
            const f32x4 v = __builtin_nontemporal_load(&x4[off]);
            acc[k].x = fmaf(v.x, w[t], acc[k].x);
            acc[k].y = fmaf(v.y, w[t], acc[k].y);
            acc[k].z = fmaf(v.z, w[t], acc[k].z);
            acc[k].w = fmaf(v.w, w[t], acc[k].w);
        }
    }

    f32x4* __restrict__ out4 = (f32x4*)out;
#pragma unroll
    for (int k = 0; k < 4; ++k) {
        __builtin_nontemporal_store(acc[k], &out4[(long)(b0 + 4 * k) * C_HW4 + p4]);
    }
}

extern "C" void kernel_launch(void* const* d_in, const int* in_sizes, int n_in,
                              void* d_out, int out_size, void* d_ws, size_t ws_size,
                              hipStream_t stream) {
    const float* x    = (const float*)d_in[0];  // [16,10,1024,14,14]
    const float* Wmat = (const float*)d_in[1];  // [1024,10]
    const float* bias = (const float*)d_in[2];  // [1024]
    float* out = (float*)d_out;                 // [16,1,1024,14,14]

    dim3 grid(C_HW4 / 256, 4);                  // (196, 4)
    conv_over_time_kernel<<<grid, dim3(256), 0, stream>>>(x, Wmat, bias, out);
}